// Round 1
// 220.740 us; speedup vs baseline: 1.2007x; 1.2007x over previous
//
#include <hip/hip_runtime.h>

#define BB 16
#define CC 3
#define HH 512
#define WW 512
#define HWP (HH*WW)
#define NMAP ((size_t)BB*HWP)

// ---------------------------------------------------------------------------
// Fully fused guided-filter stage: two chained 2D box filters in ONE pass.
//
// Block = 512 threads = one full row width of one image; each block owns CH
// output rows. Per thread (one column w):
//   - cs0/cs1: running vertical sums of the stage-input moments (s,q) over a
//     +-P row window (advanced 2 loads/row, re-reads are L1/L2 hits).
//   - phase 1 (per A-row): exchange cs through LDS row eA, horizontal-sum
//     2P+1 neighbors -> mean/var -> A,b for this pixel. A,b kept in a
//     register ring of depth RD=2P+1 (loops fully unrolled => static idx).
//   - ca/cb: running vertical sums of A,b over +-P rows (add new A-row,
//     retire ring slot).
//   - phase 2 (per output row): exchange ca through LDS row eB, horizontal
//     sum -> raw second-box sums -> emit.
// Borders: LDS halo slots are zero once; counts via cnt_h*cnt_w.
// MODE 1: input = x (compute s,q on the fly), emit ab + next-stage moments.
// MODE 2: input = interleaved (s,q) float2 map, emit ab + next moments.
// MODE 3: input = (s,q), emit folded epilogue (D-concat + 1x1 conv) directly.
// ---------------------------------------------------------------------------
template <int P, int CH, int MODE>
__global__ __launch_bounds__(512, (MODE == 3 ? 2 : 4))
void stage(const float* __restrict__ xin, const float2* __restrict__ sqin,
           float2* __restrict__ abo, float2* __restrict__ sqo,
           const float2* __restrict__ ab1, const float2* __restrict__ ab2,
           const float* __restrict__ w1, float* __restrict__ outp, float eps)
{
    constexpr int RD  = 2*P + 1;
    constexpr int LW  = 512 + 2*P;
    constexpr int NCH = HH / CH;
    __shared__ float2 eA[LW];
    __shared__ float2 eB[LW];

    const int t  = threadIdx.x;
    const int bx = blockIdx.x;
    const int b  = bx / NCH;
    const int h0 = (bx % NCH) * CH;
    const size_t mapbase = (size_t)b * HWP;
    const float*  xb  = (MODE != 2) ? (xin + (size_t)b * CC * HWP) : nullptr;
    const float2* sqb = (MODE != 1) ? (sqin + mapbase) : nullptr;

    // one-time zero halo slots (never overwritten afterwards)
    if (t < 2*P) {
        int sl = (t < P) ? t : (512 + t);
        eA[sl] = make_float2(0.f, 0.f);
        eB[sl] = make_float2(0.f, 0.f);
    }

    const int w   = t;
    const int wlo = (w - P < 0) ? 0 : w - P;
    const int whi = (w + P > WW-1) ? WW-1 : w + P;
    const float rcw = 1.0f / (float)(whi - wlo + 1);

    float cs0 = 0.f, cs1 = 0.f;   // first-box column sums (s, q)
    float ca  = 0.f, cb  = 0.f;   // second-box column sums (A, b)
    float rA[RD], rB[RD];         // A,b ring (own column, last RD A-rows)

    auto loadSQ = [&](int rr, float& sv, float& qv) {
        size_t o = (size_t)rr * WW + w;
        if constexpr (MODE == 1) {
            float x0 = xb[o], x1 = xb[o + HWP], x2 = xb[o + 2*HWP];
            sv = x0 + x1 + x2;
            qv = x0*x0 + x1*x1 + x2*x2;
        } else {
            float2 v = sqb[o];
            sv = v.x; qv = v.y;
        }
    };

    auto advance = [&](int r) {   // move cs window center r-1 -> r
        int rin = r + P, rout = r - P - 1;
        if (rin < HH)  { float sv, qv; loadSQ(rin,  sv, qv); cs0 += sv; cs1 += qv; }
        if (rout >= 0) { float sv, qv; loadSQ(rout, sv, qv); cs0 -= sv; cs1 -= qv; }
    };

    auto phase1 = [&](int r, float& Aout, float& Bout) {
        eA[t + P] = make_float2(cs0, cs1);
        __syncthreads();
        float hs0 = 0.f, hs1 = 0.f;
#pragma unroll
        for (int d = 0; d <= 2*P; ++d) { float2 v = eA[t + d]; hs0 += v.x; hs1 += v.y; }
        __syncthreads();
        int rlo = (r - P < 0) ? 0 : r - P;
        int rhi = (r + P > HH-1) ? HH-1 : r + P;
        float rNc  = (1.f/3.f) * rcw / (float)(rhi - rlo + 1);
        float mean = hs0 * rNc;
        float var  = hs1 * rNc - mean * mean;
        float A    = var / (var + eps);
        Aout = A;
        Bout = mean * (1.f - A);
    };

    float w1r[27];
    if constexpr (MODE == 3) {
#pragma unroll
        for (int k = 0; k < 27; ++k) w1r[k] = w1[k];
    }

    // prime first-box window for A-row r = h0-P  (rows h0-2P .. h0)
#pragma unroll
    for (int d = 0; d <= 2*P; ++d) {
        int rr = h0 - 2*P + d;
        if (rr >= 0) { float sv, qv; loadSQ(rr, sv, qv); cs0 += sv; cs1 += qv; }
    }

    // prime A-row ring: A-rows h0-P .. h0+P-1
#pragma unroll
    for (int j = 0; j < 2*P; ++j) {
        int r = h0 - P + j;
        if (j > 0) advance(r);
        float A = 0.f, Bv = 0.f;
        if (r >= 0) { phase1(r, A, Bv); ca += A; cb += Bv; }   // uniform branch
        rA[j % RD] = A; rB[j % RD] = Bv;
    }

    // main loop over output rows
#pragma unroll
    for (int i = 0; i < CH; ++i) {
        int r = h0 + P + i;      // new A-row entering the window
        int h = h0 + i;          // output row
        advance(r);
        float A = 0.f, Bv = 0.f;
        if (r < HH) { phase1(r, A, Bv); ca += A; cb += Bv; }   // uniform branch
        rA[(2*P + i) % RD] = A; rB[(2*P + i) % RD] = Bv;

        // phase 2: horizontal sum of second-box column sums
        eB[t + P] = make_float2(ca, cb);
        __syncthreads();
        float sA = 0.f, sB = 0.f;
#pragma unroll
        for (int d = 0; d <= 2*P; ++d) { float2 v = eB[t + d]; sA += v.x; sB += v.y; }
        __syncthreads();

        size_t oi = mapbase + (size_t)h * WW + w;
        if constexpr (MODE != 3) {
            abo[oi] = make_float2(sA, sB);               // raw box sums (x3 later)
            float sv, qv; loadSQ(h, sv, qv);             // cache-hot re-read
            float mA = 3.f * sA, mb = 3.f * sB;
            sqo[oi] = make_float2(mA*sv + 3.f*mb,
                                  mA*mA*qv + 2.f*mA*mb*sv + 3.f*mb*mb);
        } else {
            float a3 = 3.f*sA, b3 = 3.f*sB;
            float2 v1 = ab1[oi], v2 = ab2[oi];
            float a1 = 3.f*v1.x, b1 = 3.f*v1.y;
            float a2 = 3.f*v2.x, b2 = 3.f*v2.y;
            float P1 = a1,      Q1 = b1;
            float P2 = a2 * P1, Q2 = a2 * Q1 + b2;
            float P3 = a3 * P2, Q3 = a3 * Q2 + b3;
            float alpha[3] = {1.f - P1, P1 - P2, P2 - P3};
            float beta[3]  = {-Q1,      Q1 - Q2, Q2 - Q3};
            size_t xo = (size_t)h * WW + w;
            float xv0 = xb[xo], xv1 = xb[xo + HWP], xv2 = xb[xo + 2*HWP];
#pragma unroll
            for (int o = 0; o < 3; ++o) {
                float acc = 0.f;
#pragma unroll
                for (int g = 0; g < 3; ++g) {
                    float w0v = w1r[o*9 + g*3 + 0];
                    float wv1 = w1r[o*9 + g*3 + 1];
                    float w2v = w1r[o*9 + g*3 + 2];
                    acc += alpha[g] * (w0v*xv0 + wv1*xv1 + w2v*xv2)
                         + beta[g]  * (w0v + wv1 + w2v);
                }
                outp[(size_t)b * CC * HWP + (size_t)o * HWP + xo] = acc;
            }
        }
        // retire oldest A-row (local index i) from the vertical window
        ca -= rA[i % RD]; cb -= rB[i % RD];
    }
}

extern "C" void kernel_launch(void* const* d_in, const int* in_sizes, int n_in,
                              void* d_out, int out_size, void* d_ws, size_t ws_size,
                              hipStream_t stream) {
    (void)in_sizes; (void)n_in; (void)out_size; (void)ws_size;
    const float* x  = (const float*)d_in[0];
    const float* w1 = (const float*)d_in[1];
    float* out = (float*)d_out;

    float2* sq1 = (float2*)d_ws;       // F1 moments (stage-2 input)
    float2* sq2 = sq1 + NMAP;          // F2 moments (stage-3 input)
    float2* ab1 = sq2 + NMAP;          // raw (boxA, boxB) of stage 1
    float2* ab2 = ab1 + NMAP;          // raw (boxA, boxB) of stage 2

    dim3 bl(512);
    dim3 g(BB * (HH / 16));            // 512 blocks, full-width rows x 16

    // stage 1: k=3  (P=1), eps=0.16 — computes s,q from x inline
    stage<1,16,1><<<g, bl, 0, stream>>>(x, nullptr, ab1, sq1,
                                        nullptr, nullptr, nullptr, nullptr, 0.16f);
    // stage 2: k=7  (P=3), eps=0.04
    stage<3,16,2><<<g, bl, 0, stream>>>(nullptr, sq1, ab2, sq2,
                                        nullptr, nullptr, nullptr, nullptr, 0.04f);
    // stage 3: k=15 (P=7), eps=0.01 — epilogue (diffs + 1x1 conv) folded in
    stage<7,16,3><<<g, bl, 0, stream>>>(x, sq2, nullptr, nullptr,
                                        ab1, ab2, w1, out, 0.01f);
}

// Round 2
// 199.607 us; speedup vs baseline: 1.3278x; 1.1059x over previous
//
#include <hip/hip_runtime.h>

#define BB 16
#define CC 3
#define HH 512
#define WW 512
#define HWP (HH*WW)
#define NMAP ((size_t)BB*HWP)

// ---------------------------------------------------------------------------
// Fused guided-filter stage, VW=2 columns/thread, 256 threads = full 512-wide
// row. Both per-row horizontal exchanges (first-box column sums cs and
// second-box column sums ca) share ONE LDS write + barrier pair per row:
//   iter j (A-row r = h0-P+j):
//     issue global loads for rows r+1+P / r-P (latency hides under LDS sums)
//     write float4(cs.s, cs.q, ca.A, ca.b) per column (even/odd split arrays)
//     sync; 16 ds_read_b128 window -> S0,S1 (both cols, both exchanges); sync
//     emit output row r-P-1 from S*.zw ; compute A(r),b(r) from S*.xy
//     ca += A(r) - ring[j%RD]; ring push; cs += in - out
// Even/odd column split keeps lane stride = 16B (no bank conflicts).
// MODE 1: input x (s,q on the fly)  MODE 2: input (s,q) float2 map
// MODE 3: input (s,q); epilogue (diffs + 1x1 conv) folded into emit.
// ---------------------------------------------------------------------------
template <int P, int CH, int MODE>
__global__ __launch_bounds__(256, MODE == 3 ? 2 : 4)
void stage(const float* __restrict__ xin, const float2* __restrict__ sqin,
           float2* __restrict__ abo, float2* __restrict__ sqo,
           const float2* __restrict__ abp1, const float2* __restrict__ abp2,
           const float* __restrict__ wt, float* __restrict__ outp, float eps)
{
    constexpr int RD  = 2*P + 1;
    constexpr int HE  = (P+1)/2;        // halo col-pairs each side
    constexpr int NIT = CH + 2*P + 1;
    constexpr int NCH = HH / CH;
    constexpr int mm  = (P-1)/2;
    constexpr int MM  = (P+1)/2;

    __shared__ float4 ev[256 + 2*HE];   // even columns: (cs.s, cs.q, ca.A, ca.b)
    __shared__ float4 od[256 + 2*HE];   // odd columns

    const int t  = threadIdx.x;
    const int bx = blockIdx.x;
    const int b  = bx / NCH;
    const int h0 = (bx % NCH) * CH;
    const size_t mapbase = (size_t)b * HWP;
    const float*  xb  = (MODE != 2) ? (xin + (size_t)b * CC * HWP) : nullptr;
    const float2* sqb = (MODE != 1) ? (sqin + mapbase) : nullptr;

    // one-time zero halo slots (body writes never touch them)
    if (t < 2*HE) {
        int sl = (t < HE) ? t : 256 + t;
        ev[sl] = make_float4(0.f, 0.f, 0.f, 0.f);
        od[sl] = make_float4(0.f, 0.f, 0.f, 0.f);
    }

    const int wc0 = 2*t;
    const int wc1 = wc0 + 1;
    const int wlo0 = (wc0-P < 0) ? 0 : wc0-P, whi0 = (wc0+P > WW-1) ? WW-1 : wc0+P;
    const int wlo1 = (wc1-P < 0) ? 0 : wc1-P, whi1 = (wc1+P > WW-1) ? WW-1 : wc1+P;
    const float rcw0 = 1.0f / (float)(whi0 - wlo0 + 1);
    const float rcw1 = 1.0f / (float)(whi1 - wlo1 + 1);

    float2 cs0 = make_float2(0.f,0.f), cs1 = make_float2(0.f,0.f);
    float2 ca0 = make_float2(0.f,0.f), ca1 = make_float2(0.f,0.f);
    float2 rg0[RD], rg1[RD];
#pragma unroll
    for (int k = 0; k < RD; ++k) { rg0[k] = make_float2(0.f,0.f); rg1[k] = make_float2(0.f,0.f); }

    auto loadrow = [&](int rr, float2& d0, float2& d1) {
        if constexpr (MODE == 1) {
            size_t o = (size_t)rr * WW + wc0;
            float2 x0 = *(const float2*)(xb + o);
            float2 x1 = *(const float2*)(xb + o + HWP);
            float2 x2 = *(const float2*)(xb + o + 2*HWP);
            d0 = make_float2(x0.x+x1.x+x2.x, x0.x*x0.x + x1.x*x1.x + x2.x*x2.x);
            d1 = make_float2(x0.y+x1.y+x2.y, x0.y*x0.y + x1.y*x1.y + x2.y*x2.y);
        } else {
            float4 v = ((const float4*)(sqb + (size_t)rr * WW))[t];
            d0 = make_float2(v.x, v.y);
            d1 = make_float2(v.z, v.w);
        }
    };

    // prime cs: vertical window rows h0-2P .. h0 (center r = h0-P)
#pragma unroll
    for (int d = 0; d <= 2*P; ++d) {
        int rr = h0 - 2*P + d;
        if (rr >= 0) {                               // uniform
            float2 d0, d1; loadrow(rr, d0, d1);
            cs0.x += d0.x; cs0.y += d0.y; cs1.x += d1.x; cs1.y += d1.y;
        }
    }

    float w1r[27];
    if constexpr (MODE == 3) {
#pragma unroll
        for (int k = 0; k < 27; ++k) w1r[k] = wt[k];
    }

#pragma unroll
    for (int j = 0; j < NIT; ++j) {
        const int r = h0 - P + j;                    // current A-row

        // issue next-row global loads early (applied after 2nd barrier)
        float2 gi0 = make_float2(0.f,0.f), gi1 = make_float2(0.f,0.f);
        float2 go0 = make_float2(0.f,0.f), go1 = make_float2(0.f,0.f);
        if (j < NIT-1) {
            int rin = r + 1 + P, rout = r - P;
            if (rin < HH)  loadrow(rin, gi0, gi1);   // uniform
            if (rout >= 0) loadrow(rout, go0, go1);  // uniform
        }

        ev[HE+t] = make_float4(cs0.x, cs0.y, ca0.x, ca0.y);
        od[HE+t] = make_float4(cs1.x, cs1.y, ca1.x, ca1.y);
        __syncthreads();

        float4 CE = make_float4(0.f,0.f,0.f,0.f), CO = make_float4(0.f,0.f,0.f,0.f);
#pragma unroll
        for (int i = -mm; i <= mm; ++i) {
            float4 e = ev[HE+t+i], o = od[HE+t+i];
            CE.x += e.x; CE.y += e.y; CE.z += e.z; CE.w += e.w;
            CO.x += o.x; CO.y += o.y; CO.z += o.z; CO.w += o.w;
        }
        float4 eM = ev[HE+t+MM], oM = od[HE+t-MM];
        __syncthreads();

        // window sums: S0 = col wc0, S1 = col wc1 (x,y = box1 of s,q ; z,w = box2 of A,b)
        float4 S0 = make_float4(CE.x+CO.x+oM.x, CE.y+CO.y+oM.y, CE.z+CO.z+oM.z, CE.w+CO.w+oM.w);
        float4 S1 = make_float4(CE.x+CO.x+eM.x, CE.y+CO.y+eM.y, CE.z+CO.z+eM.z, CE.w+CO.w+eM.w);

        // emit output row o = r-P-1 (ca written this iter covers A-rows r-1-2P..r-1)
        if (j >= 2*P+1) {                            // uniform
            const int h = r - P - 1;
            const size_t oi = (size_t)h * WW + wc0;
            if constexpr (MODE != 3) {
                *((float4*)(abo + mapbase + oi)) = make_float4(S0.z, S0.w, S1.z, S1.w);
                float2 d0, d1; loadrow(h, d0, d1);   // cache-hot re-read
                float mA0 = 3.f*S0.z, mb0 = 3.f*S0.w;
                float mA1 = 3.f*S1.z, mb1 = 3.f*S1.w;
                *((float4*)(sqo + mapbase + oi)) = make_float4(
                    mA0*d0.x + 3.f*mb0,
                    mA0*mA0*d0.y + 2.f*mA0*mb0*d0.x + 3.f*mb0*mb0,
                    mA1*d1.x + 3.f*mb1,
                    mA1*mA1*d1.y + 2.f*mA1*mb1*d1.x + 3.f*mb1*mb1);
            } else {
                float4 v1 = *((const float4*)(abp1 + mapbase + oi));
                float4 v2 = *((const float4*)(abp2 + mapbase + oi));
                float2 xc0 = *(const float2*)(xb + oi);
                float2 xc1 = *(const float2*)(xb + oi + HWP);
                float2 xc2 = *(const float2*)(xb + oi + 2*HWP);
                float res0[3], res1[3];
#pragma unroll
                for (int c = 0; c < 2; ++c) {
                    float a1 = 3.f * (c ? v1.z : v1.x), b1 = 3.f * (c ? v1.w : v1.y);
                    float a2 = 3.f * (c ? v2.z : v2.x), b2 = 3.f * (c ? v2.w : v2.y);
                    float a3 = 3.f * (c ? S1.z : S0.z), b3 = 3.f * (c ? S1.w : S0.w);
                    float x0 = c ? xc0.y : xc0.x;
                    float x1 = c ? xc1.y : xc1.x;
                    float x2 = c ? xc2.y : xc2.x;
                    float Pp1 = a1,       Q1 = b1;
                    float Pp2 = a2 * Pp1, Q2 = a2 * Q1 + b2;
                    float Pp3 = a3 * Pp2, Q3 = a3 * Q2 + b3;
                    float al[3] = {1.f - Pp1, Pp1 - Pp2, Pp2 - Pp3};
                    float be[3] = {-Q1,       Q1 - Q2,   Q2 - Q3};
                    float* rr_ = c ? res1 : res0;
#pragma unroll
                    for (int o = 0; o < 3; ++o) {
                        float acc = 0.f;
#pragma unroll
                        for (int g = 0; g < 3; ++g) {
                            float wa = w1r[o*9 + g*3 + 0];
                            float wb = w1r[o*9 + g*3 + 1];
                            float wc = w1r[o*9 + g*3 + 2];
                            acc += al[g] * (wa*x0 + wb*x1 + wc*x2)
                                 + be[g] * (wa + wb + wc);
                        }
                        rr_[o] = acc;
                    }
                }
                float* ob = outp + (size_t)b * CC * HWP + oi;
#pragma unroll
                for (int o = 0; o < 3; ++o)
                    *((float2*)(ob + (size_t)o * HWP)) = make_float2(res0[o], res1[o]);
            }
        }

        if (j < NIT-1) {
            // A(r), b(r) from first-box sums (rows r<0 or >=HH contribute 0)
            float2 A0 = make_float2(0.f,0.f), A1 = make_float2(0.f,0.f);
            if ((unsigned)r < (unsigned)HH) {        // uniform
                const int rlo = (r-P < 0) ? 0 : r-P;
                const int rhi = (r+P > HH-1) ? HH-1 : r+P;
                const float rch = 1.0f / (float)(rhi - rlo + 1);
                const float rN0 = (1.f/3.f) * rcw0 * rch;
                const float rN1 = (1.f/3.f) * rcw1 * rch;
                float mean0 = S0.x * rN0;
                float var0  = S0.y * rN0 - mean0*mean0;
                float a0    = var0 / (var0 + eps);
                A0 = make_float2(a0, mean0 * (1.f - a0));
                float mean1 = S1.x * rN1;
                float var1  = S1.y * rN1 - mean1*mean1;
                float a1v   = var1 / (var1 + eps);
                A1 = make_float2(a1v, mean1 * (1.f - a1v));
            }
            const int ri = j % RD;                   // static under full unroll
            ca0.x += A0.x - rg0[ri].x; ca0.y += A0.y - rg0[ri].y;
            ca1.x += A1.x - rg1[ri].x; ca1.y += A1.y - rg1[ri].y;
            rg0[ri] = A0; rg1[ri] = A1;
            // apply vertical advance of first-box window
            cs0.x += gi0.x - go0.x; cs0.y += gi0.y - go0.y;
            cs1.x += gi1.x - go1.x; cs1.y += gi1.y - go1.y;
        }
    }
}

extern "C" void kernel_launch(void* const* d_in, const int* in_sizes, int n_in,
                              void* d_out, int out_size, void* d_ws, size_t ws_size,
                              hipStream_t stream) {
    (void)in_sizes; (void)n_in; (void)out_size; (void)ws_size;
    const float* x  = (const float*)d_in[0];
    const float* w1 = (const float*)d_in[1];
    float* out = (float*)d_out;

    float2* sq1 = (float2*)d_ws;       // F1 moments (stage-2 input)
    float2* sq2 = sq1 + NMAP;          // F2 moments (stage-3 input)
    float2* ab1 = sq2 + NMAP;          // raw (boxA, boxB) of stage 1
    float2* ab2 = ab1 + NMAP;          // raw (boxA, boxB) of stage 2

    dim3 bl(256);

    // stage 1: k=3  (P=1), eps=0.16 — s,q from x inline; CH=8 -> 1024 blocks
    stage<1,8,1><<<dim3(BB*(HH/8)), bl, 0, stream>>>(x, nullptr, ab1, sq1,
                                        nullptr, nullptr, nullptr, nullptr, 0.16f);
    // stage 2: k=7  (P=3), eps=0.04 ; CH=8 -> 1024 blocks
    stage<3,8,2><<<dim3(BB*(HH/8)), bl, 0, stream>>>(nullptr, sq1, ab2, sq2,
                                        nullptr, nullptr, nullptr, nullptr, 0.04f);
    // stage 3: k=15 (P=7), eps=0.01 — epilogue folded; CH=16 -> 512 blocks
    stage<7,16,3><<<dim3(BB*(HH/16)), bl, 0, stream>>>(x, sq2, nullptr, nullptr,
                                        ab1, ab2, w1, out, 0.01f);
}